// Round 18
// baseline (465.078 us; speedup 1.0000x reference)
//
#include <hip/hip_runtime.h>
#include <hip/hip_fp16.h>
#include <math.h>

#define N_NODES 20000
#define T_STEPS 6
#define F_INCH  64
#define HC      256   // gat1: H*C
#define CH      64    // hidden width

typedef _Float16 h8    __attribute__((ext_vector_type(8)));
typedef _Float16 hv2   __attribute__((ext_vector_type(2)));
typedef float    f32x4 __attribute__((ext_vector_type(4)));

__device__ __forceinline__ float fast_tanh(float x){
  float e = __expf(2.f*x);
  return 1.f - 2.f/(e + 1.f);
}

__device__ __forceinline__ float fdot2v(hv2 a, hv2 b, float c){
#if __has_builtin(__builtin_amdgcn_fdot2)
  return __builtin_amdgcn_fdot2(a, b, c, false);
#else
  return fmaf((float)a[0], (float)b[0], fmaf((float)a[1], (float)b[1], c));
#endif
}

__device__ __forceinline__ hv2 leaky2(hv2 t){
  hv2 s = t * (_Float16)0.2f;
#if __has_builtin(__builtin_elementwise_max)
  return __builtin_elementwise_max(t, s);
#else
  hv2 r;
  r[0] = (t[0] > s[0]) ? t[0] : s[0];
  r[1] = (t[1] > s[1]) ? t[1] : s[1];
  return r;
#endif
}

// ---------------- CSR build ----------------
__global__ void k_count(const int* __restrict__ dst, int E, int* __restrict__ deg){
  int e = blockIdx.x*256 + threadIdx.x;
  if (e < E) atomicAdd(&deg[dst[e]], 1);
}

__global__ void k_scan(const int* __restrict__ deg, int* __restrict__ row_start, int N){
  __shared__ int wsum[16];
  const int PT = 20;
  int tid = threadIdx.x, wid = tid >> 6, lane = tid & 63;
  int base = tid*PT;
  int loc[PT];
  int s = 0;
  #pragma unroll
  for (int j = 0; j < PT; j++){
    int i = base + j;
    int v = (i < N) ? deg[i] : 0;
    loc[j] = s;            // exclusive local prefix
    s += v;
  }
  int ss = s;
  #pragma unroll
  for (int off = 1; off < 64; off <<= 1){
    int t = __shfl_up(ss, off, 64);
    if (lane >= off) ss += t;
  }
  if (lane == 63) wsum[wid] = ss;
  __syncthreads();
  if (tid < 16){
    int w = wsum[tid];
    #pragma unroll
    for (int off = 1; off < 16; off <<= 1){
      int t = __shfl_up(w, off, 64);
      if (tid >= off) w += t;
    }
    wsum[tid] = w;
  }
  __syncthreads();
  int pre = ((wid ? wsum[wid-1] : 0)) + (ss - s);
  #pragma unroll
  for (int j = 0; j < PT; j++){
    int i = base + j;
    if (i < N) row_start[i] = pre + loc[j];
  }
  if (tid == 0) row_start[N] = wsum[15];
}

__global__ void k_scatter(const int* __restrict__ src, const int* __restrict__ dst, int E,
                          const int* __restrict__ row_start, int* __restrict__ cursor,
                          int* __restrict__ csr){
  int e = blockIdx.x*256 + threadIdx.x;
  if (e < E){
    int d = dst[e];
    int pos = atomicAdd(&cursor[d], 1);
    csr[row_start[d] + pos] = src[e];
  }
}

__global__ void k_sort(const int* __restrict__ row_start, int* __restrict__ csr, int N){
  int wid = threadIdx.x >> 6, lane = threadIdx.x & 63;
  int d = blockIdx.x*4 + wid;
  if (d >= N) return;
  int s = row_start[d], e = row_start[d+1], len = e - s;
  if (len <= 1) return;
  if (len <= 64){
    int v = (lane < len) ? csr[s + lane] : 0x7fffffff;
    int rank = 0;
    for (int j = 0; j < len; j++){
      int vj = __shfl(v, j, 64);
      rank += (int)((vj < v) | ((vj == v) & (j < lane)));
    }
    if (lane < len) csr[s + rank] = v;
  } else if (lane == 0){
    for (int i = s+1; i < e; i++){
      int key = csr[i]; int j = i-1;
      while (j >= s && csr[j] > key){ csr[j+1] = csr[j]; j--; }
      csr[j+1] = key;
    }
  }
}

// ---------------- weight pre-pack: MFMA B-frag layouts ----------------
__device__ __forceinline__ void packB_dev(const float* __restrict__ B, _Float16* __restrict__ Bf,
                                          int K, int N, int idx){
  if (idx >= K*N) return;
  int j    = idx & 7;
  int lane = (idx >> 3) & 63;
  int ntk  = idx >> 9;
  int NT = N >> 4;
  int ks = ntk / NT, nt = ntk - ks*NT;
  int k = ks*32 + ((lane >> 4) << 3) + j;
  int n = nt*16 + (lane & 15);
  Bf[idx] = (_Float16)B[k*N + n];
}

__device__ __forceinline__ void packBT_dev(const float* __restrict__ W, _Float16* __restrict__ Bf,
                                           int K, int N, int idx){
  if (idx >= K*N) return;
  int j    = idx & 7;
  int lane = (idx >> 3) & 63;
  int ntk  = idx >> 9;
  int NT = N >> 4;
  int ks = ntk / NT, nt = ntk - ks*NT;
  int k = ks*32 + ((lane >> 4) << 3) + j;
  int n = nt*16 + (lane & 15);
  Bf[idx] = (_Float16)W[n*K + k];
}

__global__ void k_packall(const float* __restrict__ bih, const float* __restrict__ bhh,
                          float* __restrict__ biasc,
                          const float* __restrict__ Wl1, _Float16* __restrict__ Bl1f,
                          const float* __restrict__ Wr1, _Float16* __restrict__ Br1f,
                          const float* __restrict__ Wl2, _Float16* __restrict__ Bl2f,
                          const float* __restrict__ Wr2, _Float16* __restrict__ Br2f,
                          const float* __restrict__ Wih, _Float16* __restrict__ Wihf,
                          const float* __restrict__ Whh, _Float16* __restrict__ Whhf){
  int grp = blockIdx.x >> 6;
  int idx = (blockIdx.x & 63)*256 + threadIdx.x;
  if (grp == 0){
    if (idx < 256) biasc[idx] = bih[idx] + bhh[idx];   // gate-major
  } else if (grp == 1){
    packB_dev(Wl1, Bl1f, 64, 256, idx);
  } else if (grp == 2){
    packB_dev(Wr1, Br1f, 64, 256, idx);
  } else if (grp == 3){
    packB_dev(Wl2, Bl2f, 256, 64, idx);
  } else if (grp == 4){
    packB_dev(Wr2, Br2f, 256, 64, idx);
  } else if (grp == 5){
    packBT_dev(Wih, Wihf, 64, 256, idx);               // gates_x = x @ Wih^T
  } else {
    packBT_dev(Whh, Whhf, 64, 256, idx);               // gates_h = h @ Whh^T
  }
}

// ---------------- Phase A: MFMA GEMM 64->256 dual for ALL t; outs fp16 ----------------
__global__ __launch_bounds__(256) void k_gemm1_all(
    const float* __restrict__ x, const _Float16* __restrict__ B1f,
    const _Float16* __restrict__ B2f,
    __half* __restrict__ xl_all, __half* __restrict__ xr_all, int M){
  __shared__ _Float16 aT[32*72];   // 32 rows x (64 k + 8 pad)
  int t = blockIdx.y;
  const float* A = x + t*F_INCH;   // row stride T_STEPS*F_INCH
  _Float16* C1 = (_Float16*)(void*)xl_all + (size_t)t*N_NODES*HC;
  _Float16* C2 = (_Float16*)(void*)xr_all + (size_t)t*N_NODES*HC;
  int tid = threadIdx.x;
  int r0 = blockIdx.x*32;
  for (int i = tid; i < 32*64; i += 256){
    int r = i >> 6, k = i & 63;
    int row = r0 + r;
    aT[r*72 + k] = (row < M) ? (_Float16)A[(size_t)row*(T_STEPS*F_INCH) + k] : (_Float16)0.f;
  }
  __syncthreads();
  int wave = tid >> 6, lane = tid & 63;
  int m = wave & 1;
  const h8* Bfrag = (const h8*)((wave >> 1) ? B2f : B1f);
  _Float16* C = (wave >> 1) ? C2 : C1;
  int arow = m*16 + (lane & 15);
  int kb = (lane >> 4) * 8;
  h8 a0 = *(const h8*)&aT[arow*72 + kb];
  h8 a1 = *(const h8*)&aT[arow*72 + 32 + kb];
  f32x4 z = {0.f, 0.f, 0.f, 0.f};
  f32x4 acc[16];
  #pragma unroll
  for (int nt = 0; nt < 16; nt++) acc[nt] = z;
  #pragma unroll
  for (int nt = 0; nt < 16; nt++){
    h8 b0 = Bfrag[nt*64 + lane];
    h8 b1 = Bfrag[(16 + nt)*64 + lane];
    acc[nt] = __builtin_amdgcn_mfma_f32_16x16x32_f16(a0, b0, acc[nt], 0, 0, 0);
    acc[nt] = __builtin_amdgcn_mfma_f32_16x16x32_f16(a1, b1, acc[nt], 0, 0, 0);
  }
  int ccol = lane & 15, crow = (lane >> 4) * 4;
  #pragma unroll
  for (int nt = 0; nt < 16; nt++){
    #pragma unroll
    for (int r = 0; r < 4; r++){
      int row = r0 + m*16 + crow + r;
      if (row < M) C[(size_t)row*256 + nt*16 + ccol] = (_Float16)acc[nt][r];
    }
  }
}

// ---------------- Phase C: MFMA GEMM 256->64 dual for ALL t; A fp16, outs fp16 ------------
__global__ __launch_bounds__(256) void k_gemm2_all(
    const __half* __restrict__ Aall, const _Float16* __restrict__ B1f,
    const _Float16* __restrict__ B2f,
    __half* __restrict__ C1h_all, __half* __restrict__ C2h_all, int M){
  __shared__ _Float16 aT[32*264];  // 32 rows x (256 k + 8 pad)
  int t = blockIdx.y;
  const _Float16* A = (const _Float16*)(const void*)Aall + (size_t)t*N_NODES*HC;
  _Float16* C1 = (_Float16*)(void*)C1h_all + (size_t)t*N_NODES*CH;
  _Float16* C2 = (_Float16*)(void*)C2h_all + (size_t)t*N_NODES*CH;
  int tid = threadIdx.x;
  int r0 = blockIdx.x*32;
  h8 zh = {(_Float16)0.f,(_Float16)0.f,(_Float16)0.f,(_Float16)0.f,
           (_Float16)0.f,(_Float16)0.f,(_Float16)0.f,(_Float16)0.f};
  for (int i = tid; i < 32*32; i += 256){
    int r = i >> 5, c = i & 31;
    int row = r0 + r;
    h8 v = zh;
    if (row < M) v = *(const h8*)&A[(size_t)row*256 + c*8];
    *(h8*)&aT[r*264 + c*8] = v;
  }
  __syncthreads();
  int wave = tid >> 6, lane = tid & 63;
  int m = wave & 1;
  const h8* Bfrag = (const h8*)((wave >> 1) ? B2f : B1f);
  _Float16* C = (wave >> 1) ? C2 : C1;
  int arow = m*16 + (lane & 15);
  int kb = (lane >> 4) * 8;
  f32x4 z = {0.f, 0.f, 0.f, 0.f};
  f32x4 acc[4];
  #pragma unroll
  for (int nt = 0; nt < 4; nt++) acc[nt] = z;
  #pragma unroll
  for (int ks = 0; ks < 8; ks++){
    h8 a = *(const h8*)&aT[arow*264 + ks*32 + kb];
    #pragma unroll
    for (int nt = 0; nt < 4; nt++){
      h8 b = Bfrag[(ks*4 + nt)*64 + lane];
      acc[nt] = __builtin_amdgcn_mfma_f32_16x16x32_f16(a, b, acc[nt], 0, 0, 0);
    }
  }
  int ccol = lane & 15, crow = (lane >> 4) * 4;
  #pragma unroll
  for (int nt = 0; nt < 4; nt++){
    #pragma unroll
    for (int r = 0; r < 4; r++){
      int row = r0 + m*16 + crow + r;
      if (row < M) C[(size_t)row*64 + nt*16 + ccol] = (_Float16)acc[nt][r];
    }
  }
}

// ---------------- Phase B: GATv2 layer 1 for ALL t; scalar-uniform control flow -----------
__global__ void k_gat1_all(const __half* __restrict__ xl_all, const __half* __restrict__ xr_all,
                           const int* __restrict__ row_start, const int* __restrict__ csr,
                           const float* __restrict__ att, const float* __restrict__ bias,
                           __half* __restrict__ out_all, int N){
  int wid = threadIdx.x >> 6, lane = threadIdx.x & 63;
  int dst = blockIdx.x*4 + wid;
  if (dst >= N) return;
  int t = blockIdx.y;
  const char* xlb = (const char*)(xl_all + (size_t)t*N_NODES*HC);
  const uint2* xrh = (const uint2*)(xr_all + (size_t)t*N_NODES*HC);
  uint2* outh = (uint2*)(out_all + (size_t)t*N_NODES*HC);
  uint2 xr_raw = xrh[(unsigned)(dst*64 + lane)];
  hv2 xr01 = *reinterpret_cast<hv2*>(&xr_raw.x);
  hv2 xr23 = *reinterpret_cast<hv2*>(&xr_raw.y);
  float4 at4 = ((const float4*)att)[lane];
  hv2 at01; at01[0] = (_Float16)at4.x; at01[1] = (_Float16)at4.y;
  hv2 at23; at23[0] = (_Float16)at4.z; at23[1] = (_Float16)at4.w;
  unsigned loff = lane*8u;
  int s0 = __builtin_amdgcn_readfirstlane(row_start[dst]);
  int s1 = __builtin_amdgcn_readfirstlane(row_start[dst+1]);
  float den = 0.f, ax = 0.f, ay = 0.f, az = 0.f, aw = 0.f;

  auto STEP = [&](uint2 raw){
    hv2 h01 = *reinterpret_cast<hv2*>(&raw.x);
    hv2 h23 = *reinterpret_cast<hv2*>(&raw.y);
    hv2 l01 = leaky2(h01 + xr01);
    hv2 l23 = leaky2(h23 + xr23);
    float p = fdot2v(l01, at01, fdot2v(l23, at23, 0.f));
    p += __shfl_xor(p, 1, 64);
    p += __shfl_xor(p, 2, 64);
    p += __shfl_xor(p, 4, 64);
    p += __shfl_xor(p, 8, 64);
    float w = __expf(p);
    den += w;
    ax = fmaf(w, (float)h01[0], ax);
    ay = fmaf(w, (float)h01[1], ay);
    az = fmaf(w, (float)h23[0], az);
    aw = fmaf(w, (float)h23[1], aw);
  };

  for (int base = s0; base < s1; base += 64){
    int rem = s1 - base;
    int cnt = rem < 64 ? rem : 64;                 // SGPR
    int idxv = (base + lane < s1) ? csr[base + lane] : 0;
    auto LD = [&](int i)->uint2 {
      int s = __builtin_amdgcn_readlane(idxv, i & 63);
      return *(const uint2*)(xlb + (((size_t)(unsigned)s) << 9) + loff);
    };
    uint2 p0=LD(0), p1=LD(1), p2=LD(2), p3=LD(3);
    uint2 p4=LD(4), p5=LD(5), p6=LD(6), p7=LD(7);
    for (int i = 0; i < cnt; i += 4){
      uint2 n0=LD(i+8), n1=LD(i+9), n2=LD(i+10), n3=LD(i+11);
      if (i + 4 <= cnt){
        STEP(p0); STEP(p1); STEP(p2); STEP(p3);
      } else {
        STEP(p0);
        if (i+1 < cnt) STEP(p1);
        if (i+2 < cnt) STEP(p2);
        if (i+3 < cnt) STEP(p3);
      }
      p0=p4; p1=p5; p2=p6; p3=p7;
      p4=n0; p5=n1; p6=n2; p7=n3;
    }
  }
  float invd = (s1 > s0) ? 1.f/den : 0.f;
  float4 b4 = ((const float4*)bias)[lane];
  float rx = fmaf(ax, invd, b4.x);
  float ry = fmaf(ay, invd, b4.y);
  float rz = fmaf(az, invd, b4.z);
  float rw = fmaf(aw, invd, b4.w);
  rx = rx > 0.f ? rx : (__expf(rx) - 1.f);
  ry = ry > 0.f ? ry : (__expf(ry) - 1.f);
  rz = rz > 0.f ? rz : (__expf(rz) - 1.f);
  rw = rw > 0.f ? rw : (__expf(rw) - 1.f);
  __half2 o01 = __floats2half2_rn(rx, ry);
  __half2 o23 = __floats2half2_rn(rz, rw);
  uint2 o;
  o.x = *reinterpret_cast<unsigned int*>(&o01);
  o.y = *reinterpret_cast<unsigned int*>(&o23);
  outh[(unsigned)(dst*64 + lane)] = o;
}

// ---------------- Phase D: GATv2 layer 2 for ALL t; scalar bounds, fp16 out ---------------
__global__ void k_gat2_all(const __half* __restrict__ xl_all, const __half* __restrict__ xr_all,
                           const int* __restrict__ row_start, const int* __restrict__ csr,
                           const float* __restrict__ att, const float* __restrict__ bias,
                           __half* __restrict__ out_all, int N){
  int wid = threadIdx.x >> 6, lane = threadIdx.x & 63;
  int dst = blockIdx.x*4 + wid;
  if (dst >= N) return;
  int t = blockIdx.y;
  int g = lane >> 4, q = lane & 15;
  const char* xlb = (const char*)(xl_all + (size_t)t*N_NODES*CH);
  const uint2* xrh = (const uint2*)(xr_all + (size_t)t*N_NODES*CH);
  uint2* outh = (uint2*)(out_all + (size_t)t*N_NODES*CH);
  uint2 xr_raw = xrh[(unsigned)(dst*16 + q)];
  hv2 xr01 = *reinterpret_cast<hv2*>(&xr_raw.x);
  hv2 xr23 = *reinterpret_cast<hv2*>(&xr_raw.y);
  float4 at4 = ((const float4*)att)[q];
  hv2 at01; at01[0] = (_Float16)at4.x; at01[1] = (_Float16)at4.y;
  hv2 at23; at23[0] = (_Float16)at4.z; at23[1] = (_Float16)at4.w;
  unsigned qoff = q*8u;
  int s0 = __builtin_amdgcn_readfirstlane(row_start[dst]);
  int s1 = __builtin_amdgcn_readfirstlane(row_start[dst+1]);
  float den = 0.f, ax = 0.f, ay = 0.f, az = 0.f, aw = 0.f;

  for (int base = s0; base < s1; base += 64){
    int rem = s1 - base;
    int cnt = rem < 64 ? rem : 64;                 // SGPR
    int idxv = (base + lane < s1) ? csr[base + lane] : 0;
    int K = (cnt + 3) >> 2;                        // SGPR trip count
    int e0 = g, e1 = g + 4;
    int sA = __shfl(idxv, e0 < cnt ? e0 : 0, 64);
    int sB = __shfl(idxv, e1 < cnt ? e1 : 0, 64);
    uint2 vA = *(const uint2*)(xlb + (((size_t)(unsigned)sA) << 7) + qoff);
    uint2 vB = *(const uint2*)(xlb + (((size_t)(unsigned)sB) << 7) + qoff);
    for (int k = 0; k < K; k++){
      int en = 4*k + 8 + g;
      int sN = __shfl(idxv, en < cnt ? en : 0, 64);
      uint2 vN = *(const uint2*)(xlb + (((size_t)(unsigned)sN) << 7) + qoff);
      int e = 4*k + g;
      if (e < cnt){
        hv2 h01 = *reinterpret_cast<hv2*>(&vA.x);
        hv2 h23 = *reinterpret_cast<hv2*>(&vA.y);
        hv2 l01 = leaky2(h01 + xr01);
        hv2 l23 = leaky2(h23 + xr23);
        float p = fdot2v(l01, at01, fdot2v(l23, at23, 0.f));
        p += __shfl_xor(p, 1, 64);
        p += __shfl_xor(p, 2, 64);
        p += __shfl_xor(p, 4, 64);
        p += __shfl_xor(p, 8, 64);
        float w = __expf(p);
        den += w;
        ax = fmaf(w, (float)h01[0], ax);
        ay = fmaf(w, (float)h01[1], ay);
        az = fmaf(w, (float)h23[0], az);
        aw = fmaf(w, (float)h23[1], aw);
      }
      vA = vB; vB = vN;
    }
  }
  den += __shfl_xor(den, 16, 64); den += __shfl_xor(den, 32, 64);
  ax  += __shfl_xor(ax, 16, 64);  ax  += __shfl_xor(ax, 32, 64);
  ay  += __shfl_xor(ay, 16, 64);  ay  += __shfl_xor(ay, 32, 64);
  az  += __shfl_xor(az, 16, 64);  az  += __shfl_xor(az, 32, 64);
  aw  += __shfl_xor(aw, 16, 64);  aw  += __shfl_xor(aw, 32, 64);
  float invd = (s1 > s0) ? 1.f/den : 0.f;
  float4 b4 = ((const float4*)bias)[q];
  float rx = fmaf(ax, invd, b4.x);
  float ry = fmaf(ay, invd, b4.y);
  float rz = fmaf(az, invd, b4.z);
  float rw = fmaf(aw, invd, b4.w);
  rx = rx > 0.f ? rx : (__expf(rx) - 1.f);
  ry = ry > 0.f ? ry : (__expf(ry) - 1.f);
  rz = rz > 0.f ? rz : (__expf(rz) - 1.f);
  rw = rw > 0.f ? rw : (__expf(rw) - 1.f);
  if (g == 0){
    __half2 o01 = __floats2half2_rn(rx, ry);
    __half2 o23 = __floats2half2_rn(rz, rw);
    uint2 o;
    o.x = *reinterpret_cast<unsigned int*>(&o01);
    o.y = *reinterpret_cast<unsigned int*>(&o23);
    outh[(unsigned)(dst*16 + q)] = o;
  }
}

// ---------------- Phase E: gates_x = h2 @ Wih^T + bias, MFMA over ALL 120000 rows ---------
__global__ __launch_bounds__(256) void k_gemmx_all(
    const __half* __restrict__ Aall, const _Float16* __restrict__ Bf,
    const float* __restrict__ biasc, __half* __restrict__ Call){
  __shared__ _Float16 aT[32*72];
  int tid = threadIdx.x;
  int r0 = blockIdx.x*32;     // 3750 blocks x 32 rows = 120000 exact
  {
    int r = tid >> 3, c8 = tid & 7;
    *(h8*)&aT[r*72 + c8*8] =
        *(const h8*)&((const _Float16*)(const void*)Aall)[((size_t)(r0+r))*64 + c8*8];
  }
  __syncthreads();
  int wave = tid >> 6, lane = tid & 63;
  int m = wave & 1, nh = wave >> 1;
  int arow = m*16 + (lane & 15);
  int kb = (lane >> 4) * 8;
  h8 a0 = *(const h8*)&aT[arow*72 + kb];
  h8 a1 = *(const h8*)&aT[arow*72 + 32 + kb];
  const h8* B = (const h8*)Bf;
  f32x4 z = {0.f, 0.f, 0.f, 0.f};
  f32x4 acc[8];
  #pragma unroll
  for (int nt = 0; nt < 8; nt++) acc[nt] = z;
  #pragma unroll
  for (int nt = 0; nt < 8; nt++){
    int ntg = nh*8 + nt;
    acc[nt] = __builtin_amdgcn_mfma_f32_16x16x32_f16(a0, B[ntg*64 + lane],        acc[nt], 0,0,0);
    acc[nt] = __builtin_amdgcn_mfma_f32_16x16x32_f16(a1, B[(16 + ntg)*64 + lane], acc[nt], 0,0,0);
  }
  int ccol = lane & 15, crow = (lane >> 4) * 4;
  _Float16* C = (_Float16*)(void*)Call;
  #pragma unroll
  for (int nt = 0; nt < 8; nt++){
    int ntg = nh*8 + nt;
    int col = ntg*16 + ccol;
    float b = biasc[col];
    #pragma unroll
    for (int r = 0; r < 4; r++){
      C[(size_t)(r0 + m*16 + crow + r)*256 + col] = (_Float16)(acc[nt][r] + b);
    }
  }
}

// ---------------- Fused recurrent LSTM + MLP: Whh B-frags staged in LDS -------------------
// 625 blocks x 4 waves x 8 rows (20000 exact). Whh B-frag set (32KB + swizzle pad)
// staged to LDS once per block -> per-step B delivery is ds_read, not L2.
// Swizzle: h8 chunk i stored at half offset i*8 + (i>>3)*8 (breaks 8-way bank conflict).
// h lives in per-wave A-tile (wave-synchronous, no barriers after the initial one).
__global__ __launch_bounds__(256) void k_lstm_rec(
    const __half* __restrict__ gatesx,    // [T*N][256] fp16 (bias included)
    const _Float16* __restrict__ Whhf,    // 64x256 B-frag, gate-major cols
    const float* __restrict__ Wfc1, const float* __restrict__ bfc1,
    const float* __restrict__ Wout, const float* __restrict__ bout,
    float* __restrict__ out, int N){
  __shared__ _Float16 BS[2048*8 + 2048];   // 36KB swizzled B-frags
  __shared__ _Float16 aT[4][16*72];        // per-wave h tile [row][64+8]
  __shared__ _Float16 gxT[4][8*264];       // per-wave gates_x tile [row][256+8]
  int tid = threadIdx.x, w = tid >> 6, lane = tid & 63;
  int r0 = blockIdx.x*32 + w*8;
  for (int i = tid; i < 2048; i += 256){
    *(h8*)&BS[i*8 + ((i >> 3) << 3)] = *(const h8*)&Whhf[(size_t)i*8];
  }
  _Float16* A  = aT[w];
  _Float16* GX = gxT[w];
  for (int i = lane; i < 16*72; i += 64) A[i] = (_Float16)0.f;
  __syncthreads();                        // BS staged, A zeroed
  int ccol = lane & 15, crow = (lane >> 4) * 4;
  bool valid = crow < 8;                  // lanes owning real rows
  int arow = lane & 15;
  int kb = (lane >> 4) * 8;
  const _Float16* gxb = (const _Float16*)(const void*)gatesx;
  float c[16];
  #pragma unroll
  for (int i = 0; i < 16; i++) c[i] = 0.f;

  for (int t = 0; t < T_STEPS; t++){
    #pragma unroll
    for (int it = 0; it < 4; it++){       // stage 8 rows x 256 gates_x (4KB), coalesced
      int idx = it*64 + lane;
      int r = idx >> 5, c8 = idx & 31;
      *(h8*)&GX[r*264 + c8*8] = *(const h8*)&gxb[((size_t)t*N_NODES + r0 + r)*256 + c8*8];
    }
    h8 a0 = *(const h8*)&A[arow*72 + kb];
    h8 a1 = *(const h8*)&A[arow*72 + 32 + kb];
    f32x4 z = {0.f, 0.f, 0.f, 0.f};
    f32x4 acc[16];
    #pragma unroll
    for (int nt = 0; nt < 16; nt++) acc[nt] = z;
    #pragma unroll
    for (int nt = 0; nt < 16; nt++){
      int i0 = nt*64 + lane;
      int i1 = (16 + nt)*64 + lane;
      h8 b0 = *(const h8*)&BS[i0*8 + ((i0 >> 3) << 3)];
      h8 b1 = *(const h8*)&BS[i1*8 + ((i1 >> 3) << 3)];
      acc[nt] = __builtin_amdgcn_mfma_f32_16x16x32_f16(a0, b0, acc[nt], 0, 0, 0);
      acc[nt] = __builtin_amdgcn_mfma_f32_16x16x32_f16(a1, b1, acc[nt], 0, 0, 0);
    }
    if (valid){
      #pragma unroll
      for (int us = 0; us < 4; us++){
        int ucol = us*16 + ccol;
        #pragma unroll
        for (int r = 0; r < 4; r++){
          int row = crow + r;               // 0..7
          float gi = acc[us     ][r] + (float)GX[row*264 +       ucol];
          float gf = acc[4  + us][r] + (float)GX[row*264 +  64 + ucol];
          float gg = acc[8  + us][r] + (float)GX[row*264 + 128 + ucol];
          float go = acc[12 + us][r] + (float)GX[row*264 + 192 + ucol];
          float I = 1.f/(1.f + __expf(-gi));
          float F = 1.f/(1.f + __expf(-gf));
          float O = 1.f/(1.f + __expf(-go));
          float G = fast_tanh(gg);
          float cc = fmaf(F, c[us*4 + r], I*G);
          c[us*4 + r] = cc;
          A[row*72 + ucol] = (_Float16)(O * fast_tanh(cc));
        }
      }
    }
  }
  // ---- fused MLP head: 8 lanes/row, 4 hidden cols each ----
  int rowm = lane >> 3;            // 0..7
  int cb = (lane & 7) * 4;         // hidden col quad
  float a4[4];
  #pragma unroll
  for (int j = 0; j < 4; j++) a4[j] = bfc1[cb + j];
  for (int k = 0; k < 64; k++){
    float hv = (float)A[rowm*72 + k];
    #pragma unroll
    for (int j = 0; j < 4; j++) a4[j] = fmaf(hv, Wfc1[k*32 + cb + j], a4[j]);
  }
  float v = 0.f;
  #pragma unroll
  for (int j = 0; j < 4; j++) v += fmaxf(a4[j], 0.f) * Wout[cb + j];
  v += __shfl_xor(v, 1, 64);
  v += __shfl_xor(v, 2, 64);
  v += __shfl_xor(v, 4, 64);
  if ((lane & 7) == 0) out[r0 + rowm] = v + bout[0];
}

// ---------------- launch ----------------
extern "C" void kernel_launch(void* const* d_in, const int* in_sizes, int n_in,
                              void* d_out, int out_size, void* d_ws, size_t ws_size,
                              hipStream_t stream){
  const float* x    = (const float*)d_in[0];
  const int*   edge = (const int*)  d_in[1];
  const float* Wl1  = (const float*)d_in[2];
  const float* Wr1  = (const float*)d_in[3];
  const float* att1 = (const float*)d_in[4];
  const float* b1   = (const float*)d_in[5];
  const float* Wl2  = (const float*)d_in[6];
  const float* Wr2  = (const float*)d_in[7];
  const float* att2 = (const float*)d_in[8];
  const float* b2   = (const float*)d_in[9];
  const float* Wih  = (const float*)d_in[10];
  const float* Whh  = (const float*)d_in[11];
  const float* bih  = (const float*)d_in[12];
  const float* bhh  = (const float*)d_in[13];
  const float* Wfc1 = (const float*)d_in[14];
  const float* bfc1 = (const float*)d_in[15];
  const float* Wout = (const float*)d_in[16];
  const float* bout = (const float*)d_in[17];
  float* out = (float*)d_out;

  const int N = N_NODES;
  const int E = in_sizes[1] / 2;

  char* p = (char*)d_ws;
  auto alloc = [&](size_t bytes)->char*{ char* q = p; p += (bytes + 255) & ~(size_t)255; return q; };
  int* csr       = (int*)alloc((size_t)E*sizeof(int));
  int* row_start = (int*)alloc((size_t)(N+1)*sizeof(int));
  int* deg       = (int*)alloc((size_t)N*sizeof(int));
  int* cursor    = (int*)alloc((size_t)N*sizeof(int));
  const size_t NB = (size_t)T_STEPS*N_NODES*HC;      // 30.72M elems
  char* bufA = alloc(NB*2);   // 61.44MB
  char* bufB = alloc(NB*2);   // 61.44MB
  char* bufC = alloc(NB*2);   // 61.44MB
  float* biasc  = (float*)alloc(256*4);
  _Float16* Bl1f = (_Float16*)alloc(64*256*2);   // MFMA B-frag packs
  _Float16* Br1f = (_Float16*)alloc(64*256*2);
  _Float16* Bl2f = (_Float16*)alloc(256*64*2);
  _Float16* Br2f = (_Float16*)alloc(256*64*2);
  _Float16* Wihf = (_Float16*)alloc(64*256*2);
  _Float16* Whhf = (_Float16*)alloc(64*256*2);

  // Phase aliasing (stream-ordered; each buffer's old tenant dead before reuse):
  __half* xl1h_all = (__half*)bufA;                   // A out, B in
  __half* xr1h_all = (__half*)bufB;                   // A out, B in
  __half* h1_all   = (__half*)bufC;                   // B out, C in
  __half* xl2h_all = (__half*)bufA;                   // C out, D in (xl1h dead)
  __half* xr2h_all = (__half*)(bufA + (size_t)T_STEPS*N_NODES*CH*2);
  __half* h2f_all  = (__half*)bufB;                   // D out (fp16), E in
  __half* gatesx   = (__half*)bufC;                   // E out (h1 dead), rec in

  const int* srcIdx = edge;       // edge_index[0]
  const int* dstIdx = edge + E;   // edge_index[1]

  // deg and cursor are adjacent allocations -> one memset covers both (incl. pad)
  hipMemsetAsync(deg, 0, (size_t)((char*)cursor - (char*)deg) + (size_t)N*4, stream);

  k_count  <<<(E+255)/256, 256, 0, stream>>>(dstIdx, E, deg);
  k_scan   <<<1, 1024, 0, stream>>>(deg, row_start, N);
  k_scatter<<<(E+255)/256, 256, 0, stream>>>(srcIdx, dstIdx, E, row_start, cursor, csr);
  k_sort   <<<(N+3)/4, 256, 0, stream>>>(row_start, csr, N);
  k_packall<<<448, 256, 0, stream>>>(bih, bhh, biasc,
                                     Wl1, Bl1f, Wr1, Br1f, Wl2, Bl2f, Wr2, Br2f,
                                     Wih, Wihf, Whh, Whhf);

  dim3 gGemm((N+31)/32, T_STEPS);
  dim3 gGat ((N+3)/4,  T_STEPS);
  k_gemm1_all<<<gGemm, 256, 0, stream>>>(x, Bl1f, Br1f, xl1h_all, xr1h_all, N);
  k_gat1_all <<<gGat,  256, 0, stream>>>(xl1h_all, xr1h_all, row_start, csr, att1, b1, h1_all, N);
  k_gemm2_all<<<gGemm, 256, 0, stream>>>(h1_all, Bl2f, Br2f, xl2h_all, xr2h_all, N);
  k_gat2_all <<<gGat,  256, 0, stream>>>(xl2h_all, xr2h_all, row_start, csr, att2, b2, h2f_all, N);

  k_gemmx_all<<<(T_STEPS*N)/32, 256, 0, stream>>>(h2f_all, Wihf, biasc, gatesx);
  k_lstm_rec <<<N/32, 256, 0, stream>>>(gatesx, Whhf, Wfc1, bfc1, Wout, bout, out, N);
}

// Round 19
// 403.216 us; speedup vs baseline: 1.1534x; 1.1534x over previous
//
#include <hip/hip_runtime.h>
#include <hip/hip_fp16.h>
#include <math.h>

#define N_NODES 20000
#define T_STEPS 6
#define F_INCH  64
#define HC      256   // gat1: H*C
#define CH      64    // hidden width

typedef _Float16 h8    __attribute__((ext_vector_type(8)));
typedef _Float16 hv2   __attribute__((ext_vector_type(2)));
typedef float    f32x4 __attribute__((ext_vector_type(4)));

__device__ __forceinline__ float fast_tanh(float x){
  float e = __expf(2.f*x);
  return 1.f - 2.f/(e + 1.f);
}

__device__ __forceinline__ float fdot2v(hv2 a, hv2 b, float c){
#if __has_builtin(__builtin_amdgcn_fdot2)
  return __builtin_amdgcn_fdot2(a, b, c, false);
#else
  return fmaf((float)a[0], (float)b[0], fmaf((float)a[1], (float)b[1], c));
#endif
}

__device__ __forceinline__ hv2 leaky2(hv2 t){
  hv2 s = t * (_Float16)0.2f;
#if __has_builtin(__builtin_elementwise_max)
  return __builtin_elementwise_max(t, s);
#else
  hv2 r;
  r[0] = (t[0] > s[0]) ? t[0] : s[0];
  r[1] = (t[1] > s[1]) ? t[1] : s[1];
  return r;
#endif
}

// ---------------- CSR build ----------------
__global__ void k_count(const int* __restrict__ dst, int E, int* __restrict__ deg){
  int e = blockIdx.x*256 + threadIdx.x;
  if (e < E) atomicAdd(&deg[dst[e]], 1);
}

__global__ void k_scan(const int* __restrict__ deg, int* __restrict__ row_start, int N){
  __shared__ int wsum[16];
  const int PT = 20;
  int tid = threadIdx.x, wid = tid >> 6, lane = tid & 63;
  int base = tid*PT;
  int loc[PT];
  int s = 0;
  #pragma unroll
  for (int j = 0; j < PT; j++){
    int i = base + j;
    int v = (i < N) ? deg[i] : 0;
    loc[j] = s;            // exclusive local prefix
    s += v;
  }
  int ss = s;
  #pragma unroll
  for (int off = 1; off < 64; off <<= 1){
    int t = __shfl_up(ss, off, 64);
    if (lane >= off) ss += t;
  }
  if (lane == 63) wsum[wid] = ss;
  __syncthreads();
  if (tid < 16){
    int w = wsum[tid];
    #pragma unroll
    for (int off = 1; off < 16; off <<= 1){
      int t = __shfl_up(w, off, 64);
      if (tid >= off) w += t;
    }
    wsum[tid] = w;
  }
  __syncthreads();
  int pre = ((wid ? wsum[wid-1] : 0)) + (ss - s);
  #pragma unroll
  for (int j = 0; j < PT; j++){
    int i = base + j;
    if (i < N) row_start[i] = pre + loc[j];
  }
  if (tid == 0) row_start[N] = wsum[15];
}

__global__ void k_scatter(const int* __restrict__ src, const int* __restrict__ dst, int E,
                          const int* __restrict__ row_start, int* __restrict__ cursor,
                          int* __restrict__ csr){
  int e = blockIdx.x*256 + threadIdx.x;
  if (e < E){
    int d = dst[e];
    int pos = atomicAdd(&cursor[d], 1);
    csr[row_start[d] + pos] = src[e];
  }
}

__global__ void k_sort(const int* __restrict__ row_start, int* __restrict__ csr, int N){
  int wid = threadIdx.x >> 6, lane = threadIdx.x & 63;
  int d = blockIdx.x*4 + wid;
  if (d >= N) return;
  int s = row_start[d], e = row_start[d+1], len = e - s;
  if (len <= 1) return;
  if (len <= 64){
    int v = (lane < len) ? csr[s + lane] : 0x7fffffff;
    int rank = 0;
    for (int j = 0; j < len; j++){
      int vj = __shfl(v, j, 64);
      rank += (int)((vj < v) | ((vj == v) & (j < lane)));
    }
    if (lane < len) csr[s + rank] = v;
  } else if (lane == 0){
    for (int i = s+1; i < e; i++){
      int key = csr[i]; int j = i-1;
      while (j >= s && csr[j] > key){ csr[j+1] = csr[j]; j--; }
      csr[j+1] = key;
    }
  }
}

// ---------------- weight pre-pack: MFMA B-frag layouts ----------------
__device__ __forceinline__ void packB_dev(const float* __restrict__ B, _Float16* __restrict__ Bf,
                                          int K, int N, int idx){
  if (idx >= K*N) return;
  int j    = idx & 7;
  int lane = (idx >> 3) & 63;
  int ntk  = idx >> 9;
  int NT = N >> 4;
  int ks = ntk / NT, nt = ntk - ks*NT;
  int k = ks*32 + ((lane >> 4) << 3) + j;
  int n = nt*16 + (lane & 15);
  Bf[idx] = (_Float16)B[k*N + n];
}

__device__ __forceinline__ void packBT_dev(const float* __restrict__ W, _Float16* __restrict__ Bf,
                                           int K, int N, int idx){
  if (idx >= K*N) return;
  int j    = idx & 7;
  int lane = (idx >> 3) & 63;
  int ntk  = idx >> 9;
  int NT = N >> 4;
  int ks = ntk / NT, nt = ntk - ks*NT;
  int k = ks*32 + ((lane >> 4) << 3) + j;
  int n = nt*16 + (lane & 15);
  Bf[idx] = (_Float16)W[n*K + k];
}

__global__ void k_packall(const float* __restrict__ bih, const float* __restrict__ bhh,
                          float* __restrict__ biasc,
                          const float* __restrict__ Wl1, _Float16* __restrict__ Bl1f,
                          const float* __restrict__ Wr1, _Float16* __restrict__ Br1f,
                          const float* __restrict__ Wl2, _Float16* __restrict__ Bl2f,
                          const float* __restrict__ Wr2, _Float16* __restrict__ Br2f,
                          const float* __restrict__ Wih, _Float16* __restrict__ Wihf,
                          const float* __restrict__ Whh, _Float16* __restrict__ Whhf){
  int grp = blockIdx.x >> 6;
  int idx = (blockIdx.x & 63)*256 + threadIdx.x;
  if (grp == 0){
    if (idx < 256) biasc[idx] = bih[idx] + bhh[idx];   // gate-major
  } else if (grp == 1){
    packB_dev(Wl1, Bl1f, 64, 256, idx);
  } else if (grp == 2){
    packB_dev(Wr1, Br1f, 64, 256, idx);
  } else if (grp == 3){
    packB_dev(Wl2, Bl2f, 256, 64, idx);
  } else if (grp == 4){
    packB_dev(Wr2, Br2f, 256, 64, idx);
  } else if (grp == 5){
    packBT_dev(Wih, Wihf, 64, 256, idx);               // gates_x = x @ Wih^T
  } else {
    packBT_dev(Whh, Whhf, 64, 256, idx);               // gates_h = h @ Whh^T
  }
}

// ---------------- Phase A: MFMA GEMM 64->256 dual for ALL t; outs fp16 ----------------
__global__ __launch_bounds__(256) void k_gemm1_all(
    const float* __restrict__ x, const _Float16* __restrict__ B1f,
    const _Float16* __restrict__ B2f,
    __half* __restrict__ xl_all, __half* __restrict__ xr_all, int M){
  __shared__ _Float16 aT[32*72];   // 32 rows x (64 k + 8 pad)
  int t = blockIdx.y;
  const float* A = x + t*F_INCH;   // row stride T_STEPS*F_INCH
  _Float16* C1 = (_Float16*)(void*)xl_all + (size_t)t*N_NODES*HC;
  _Float16* C2 = (_Float16*)(void*)xr_all + (size_t)t*N_NODES*HC;
  int tid = threadIdx.x;
  int r0 = blockIdx.x*32;
  for (int i = tid; i < 32*64; i += 256){
    int r = i >> 6, k = i & 63;
    int row = r0 + r;
    aT[r*72 + k] = (row < M) ? (_Float16)A[(size_t)row*(T_STEPS*F_INCH) + k] : (_Float16)0.f;
  }
  __syncthreads();
  int wave = tid >> 6, lane = tid & 63;
  int m = wave & 1;
  const h8* Bfrag = (const h8*)((wave >> 1) ? B2f : B1f);
  _Float16* C = (wave >> 1) ? C2 : C1;
  int arow = m*16 + (lane & 15);
  int kb = (lane >> 4) * 8;
  h8 a0 = *(const h8*)&aT[arow*72 + kb];
  h8 a1 = *(const h8*)&aT[arow*72 + 32 + kb];
  f32x4 z = {0.f, 0.f, 0.f, 0.f};
  f32x4 acc[16];
  #pragma unroll
  for (int nt = 0; nt < 16; nt++) acc[nt] = z;
  #pragma unroll
  for (int nt = 0; nt < 16; nt++){
    h8 b0 = Bfrag[nt*64 + lane];
    h8 b1 = Bfrag[(16 + nt)*64 + lane];
    acc[nt] = __builtin_amdgcn_mfma_f32_16x16x32_f16(a0, b0, acc[nt], 0, 0, 0);
    acc[nt] = __builtin_amdgcn_mfma_f32_16x16x32_f16(a1, b1, acc[nt], 0, 0, 0);
  }
  int ccol = lane & 15, crow = (lane >> 4) * 4;
  #pragma unroll
  for (int nt = 0; nt < 16; nt++){
    #pragma unroll
    for (int r = 0; r < 4; r++){
      int row = r0 + m*16 + crow + r;
      if (row < M) C[(size_t)row*256 + nt*16 + ccol] = (_Float16)acc[nt][r];
    }
  }
}

// ---------------- Phase C: MFMA GEMM 256->64 dual for ALL t; A fp16, outs fp16 ------------
__global__ __launch_bounds__(256) void k_gemm2_all(
    const __half* __restrict__ Aall, const _Float16* __restrict__ B1f,
    const _Float16* __restrict__ B2f,
    __half* __restrict__ C1h_all, __half* __restrict__ C2h_all, int M){
  __shared__ _Float16 aT[32*264];  // 32 rows x (256 k + 8 pad)
  int t = blockIdx.y;
  const _Float16* A = (const _Float16*)(const void*)Aall + (size_t)t*N_NODES*HC;
  _Float16* C1 = (_Float16*)(void*)C1h_all + (size_t)t*N_NODES*CH;
  _Float16* C2 = (_Float16*)(void*)C2h_all + (size_t)t*N_NODES*CH;
  int tid = threadIdx.x;
  int r0 = blockIdx.x*32;
  h8 zh = {(_Float16)0.f,(_Float16)0.f,(_Float16)0.f,(_Float16)0.f,
           (_Float16)0.f,(_Float16)0.f,(_Float16)0.f,(_Float16)0.f};
  for (int i = tid; i < 32*32; i += 256){
    int r = i >> 5, c = i & 31;
    int row = r0 + r;
    h8 v = zh;
    if (row < M) v = *(const h8*)&A[(size_t)row*256 + c*8];
    *(h8*)&aT[r*264 + c*8] = v;
  }
  __syncthreads();
  int wave = tid >> 6, lane = tid & 63;
  int m = wave & 1;
  const h8* Bfrag = (const h8*)((wave >> 1) ? B2f : B1f);
  _Float16* C = (wave >> 1) ? C2 : C1;
  int arow = m*16 + (lane & 15);
  int kb = (lane >> 4) * 8;
  f32x4 z = {0.f, 0.f, 0.f, 0.f};
  f32x4 acc[4];
  #pragma unroll
  for (int nt = 0; nt < 4; nt++) acc[nt] = z;
  #pragma unroll
  for (int ks = 0; ks < 8; ks++){
    h8 a = *(const h8*)&aT[arow*264 + ks*32 + kb];
    #pragma unroll
    for (int nt = 0; nt < 4; nt++){
      h8 b = Bfrag[(ks*4 + nt)*64 + lane];
      acc[nt] = __builtin_amdgcn_mfma_f32_16x16x32_f16(a, b, acc[nt], 0, 0, 0);
    }
  }
  int ccol = lane & 15, crow = (lane >> 4) * 4;
  #pragma unroll
  for (int nt = 0; nt < 4; nt++){
    #pragma unroll
    for (int r = 0; r < 4; r++){
      int row = r0 + m*16 + crow + r;
      if (row < M) C[(size_t)row*64 + nt*16 + ccol] = (_Float16)acc[nt][r];
    }
  }
}

// ---------------- Phase B: GATv2 layer 1 for ALL t; scalar-uniform control flow -----------
__global__ void k_gat1_all(const __half* __restrict__ xl_all, const __half* __restrict__ xr_all,
                           const int* __restrict__ row_start, const int* __restrict__ csr,
                           const float* __restrict__ att, const float* __restrict__ bias,
                           __half* __restrict__ out_all, int N){
  int wid = threadIdx.x >> 6, lane = threadIdx.x & 63;
  int dst = blockIdx.x*4 + wid;
  if (dst >= N) return;
  int t = blockIdx.y;
  const char* xlb = (const char*)(xl_all + (size_t)t*N_NODES*HC);
  const uint2* xrh = (const uint2*)(xr_all + (size_t)t*N_NODES*HC);
  uint2* outh = (uint2*)(out_all + (size_t)t*N_NODES*HC);
  uint2 xr_raw = xrh[(unsigned)(dst*64 + lane)];
  hv2 xr01 = *reinterpret_cast<hv2*>(&xr_raw.x);
  hv2 xr23 = *reinterpret_cast<hv2*>(&xr_raw.y);
  float4 at4 = ((const float4*)att)[lane];
  hv2 at01; at01[0] = (_Float16)at4.x; at01[1] = (_Float16)at4.y;
  hv2 at23; at23[0] = (_Float16)at4.z; at23[1] = (_Float16)at4.w;
  unsigned loff = lane*8u;
  int s0 = __builtin_amdgcn_readfirstlane(row_start[dst]);
  int s1 = __builtin_amdgcn_readfirstlane(row_start[dst+1]);
  float den = 0.f, ax = 0.f, ay = 0.f, az = 0.f, aw = 0.f;

  auto STEP = [&](uint2 raw){
    hv2 h01 = *reinterpret_cast<hv2*>(&raw.x);
    hv2 h23 = *reinterpret_cast<hv2*>(&raw.y);
    hv2 l01 = leaky2(h01 + xr01);
    hv2 l23 = leaky2(h23 + xr23);
    float p = fdot2v(l01, at01, fdot2v(l23, at23, 0.f));
    p += __shfl_xor(p, 1, 64);
    p += __shfl_xor(p, 2, 64);
    p += __shfl_xor(p, 4, 64);
    p += __shfl_xor(p, 8, 64);
    float w = __expf(p);
    den += w;
    ax = fmaf(w, (float)h01[0], ax);
    ay = fmaf(w, (float)h01[1], ay);
    az = fmaf(w, (float)h23[0], az);
    aw = fmaf(w, (float)h23[1], aw);
  };

  for (int base = s0; base < s1; base += 64){
    int rem = s1 - base;
    int cnt = rem < 64 ? rem : 64;                 // SGPR
    int idxv = (base + lane < s1) ? csr[base + lane] : 0;
    auto LD = [&](int i)->uint2 {
      int s = __builtin_amdgcn_readlane(idxv, i & 63);
      return *(const uint2*)(xlb + (((size_t)(unsigned)s) << 9) + loff);
    };
    uint2 p0=LD(0), p1=LD(1), p2=LD(2), p3=LD(3);
    uint2 p4=LD(4), p5=LD(5), p6=LD(6), p7=LD(7);
    for (int i = 0; i < cnt; i += 4){
      uint2 n0=LD(i+8), n1=LD(i+9), n2=LD(i+10), n3=LD(i+11);
      if (i + 4 <= cnt){
        STEP(p0); STEP(p1); STEP(p2); STEP(p3);
      } else {
        STEP(p0);
        if (i+1 < cnt) STEP(p1);
        if (i+2 < cnt) STEP(p2);
        if (i+3 < cnt) STEP(p3);
      }
      p0=p4; p1=p5; p2=p6; p3=p7;
      p4=n0; p5=n1; p6=n2; p7=n3;
    }
  }
  float invd = (s1 > s0) ? 1.f/den : 0.f;
  float4 b4 = ((const float4*)bias)[lane];
  float rx = fmaf(ax, invd, b4.x);
  float ry = fmaf(ay, invd, b4.y);
  float rz = fmaf(az, invd, b4.z);
  float rw = fmaf(aw, invd, b4.w);
  rx = rx > 0.f ? rx : (__expf(rx) - 1.f);
  ry = ry > 0.f ? ry : (__expf(ry) - 1.f);
  rz = rz > 0.f ? rz : (__expf(rz) - 1.f);
  rw = rw > 0.f ? rw : (__expf(rw) - 1.f);
  __half2 o01 = __floats2half2_rn(rx, ry);
  __half2 o23 = __floats2half2_rn(rz, rw);
  uint2 o;
  o.x = *reinterpret_cast<unsigned int*>(&o01);
  o.y = *reinterpret_cast<unsigned int*>(&o23);
  outh[(unsigned)(dst*64 + lane)] = o;
}

// ---------------- Phase D: GATv2 layer 2 for ALL t; scalar bounds, fp16 out ---------------
__global__ void k_gat2_all(const __half* __restrict__ xl_all, const __half* __restrict__ xr_all,
                           const int* __restrict__ row_start, const int* __restrict__ csr,
                           const float* __restrict__ att, const float* __restrict__ bias,
                           __half* __restrict__ out_all, int N){
  int wid = threadIdx.x >> 6, lane = threadIdx.x & 63;
  int dst = blockIdx.x*4 + wid;
  if (dst >= N) return;
  int t = blockIdx.y;
  int g = lane >> 4, q = lane & 15;
  const char* xlb = (const char*)(xl_all + (size_t)t*N_NODES*CH);
  const uint2* xrh = (const uint2*)(xr_all + (size_t)t*N_NODES*CH);
  uint2* outh = (uint2*)(out_all + (size_t)t*N_NODES*CH);
  uint2 xr_raw = xrh[(unsigned)(dst*16 + q)];
  hv2 xr01 = *reinterpret_cast<hv2*>(&xr_raw.x);
  hv2 xr23 = *reinterpret_cast<hv2*>(&xr_raw.y);
  float4 at4 = ((const float4*)att)[q];
  hv2 at01; at01[0] = (_Float16)at4.x; at01[1] = (_Float16)at4.y;
  hv2 at23; at23[0] = (_Float16)at4.z; at23[1] = (_Float16)at4.w;
  unsigned qoff = q*8u;
  int s0 = __builtin_amdgcn_readfirstlane(row_start[dst]);
  int s1 = __builtin_amdgcn_readfirstlane(row_start[dst+1]);
  float den = 0.f, ax = 0.f, ay = 0.f, az = 0.f, aw = 0.f;

  for (int base = s0; base < s1; base += 64){
    int rem = s1 - base;
    int cnt = rem < 64 ? rem : 64;                 // SGPR
    int idxv = (base + lane < s1) ? csr[base + lane] : 0;
    int K = (cnt + 3) >> 2;                        // SGPR trip count
    int e0 = g, e1 = g + 4;
    int sA = __shfl(idxv, e0 < cnt ? e0 : 0, 64);
    int sB = __shfl(idxv, e1 < cnt ? e1 : 0, 64);
    uint2 vA = *(const uint2*)(xlb + (((size_t)(unsigned)sA) << 7) + qoff);
    uint2 vB = *(const uint2*)(xlb + (((size_t)(unsigned)sB) << 7) + qoff);
    for (int k = 0; k < K; k++){
      int en = 4*k + 8 + g;
      int sN = __shfl(idxv, en < cnt ? en : 0, 64);
      uint2 vN = *(const uint2*)(xlb + (((size_t)(unsigned)sN) << 7) + qoff);
      int e = 4*k + g;
      if (e < cnt){
        hv2 h01 = *reinterpret_cast<hv2*>(&vA.x);
        hv2 h23 = *reinterpret_cast<hv2*>(&vA.y);
        hv2 l01 = leaky2(h01 + xr01);
        hv2 l23 = leaky2(h23 + xr23);
        float p = fdot2v(l01, at01, fdot2v(l23, at23, 0.f));
        p += __shfl_xor(p, 1, 64);
        p += __shfl_xor(p, 2, 64);
        p += __shfl_xor(p, 4, 64);
        p += __shfl_xor(p, 8, 64);
        float w = __expf(p);
        den += w;
        ax = fmaf(w, (float)h01[0], ax);
        ay = fmaf(w, (float)h01[1], ay);
        az = fmaf(w, (float)h23[0], az);
        aw = fmaf(w, (float)h23[1], aw);
      }
      vA = vB; vB = vN;
    }
  }
  den += __shfl_xor(den, 16, 64); den += __shfl_xor(den, 32, 64);
  ax  += __shfl_xor(ax, 16, 64);  ax  += __shfl_xor(ax, 32, 64);
  ay  += __shfl_xor(ay, 16, 64);  ay  += __shfl_xor(ay, 32, 64);
  az  += __shfl_xor(az, 16, 64);  az  += __shfl_xor(az, 32, 64);
  aw  += __shfl_xor(aw, 16, 64);  aw  += __shfl_xor(aw, 32, 64);
  float invd = (s1 > s0) ? 1.f/den : 0.f;
  float4 b4 = ((const float4*)bias)[q];
  float rx = fmaf(ax, invd, b4.x);
  float ry = fmaf(ay, invd, b4.y);
  float rz = fmaf(az, invd, b4.z);
  float rw = fmaf(aw, invd, b4.w);
  rx = rx > 0.f ? rx : (__expf(rx) - 1.f);
  ry = ry > 0.f ? ry : (__expf(ry) - 1.f);
  rz = rz > 0.f ? rz : (__expf(rz) - 1.f);
  rw = rw > 0.f ? rw : (__expf(rw) - 1.f);
  if (g == 0){
    __half2 o01 = __floats2half2_rn(rx, ry);
    __half2 o23 = __floats2half2_rn(rz, rw);
    uint2 o;
    o.x = *reinterpret_cast<unsigned int*>(&o01);
    o.y = *reinterpret_cast<unsigned int*>(&o23);
    outh[(unsigned)(dst*16 + q)] = o;
  }
}

// ---------------- Phase E: gates_x = h2 @ Wih^T + bias, MFMA over ALL 120000 rows ---------
__global__ __launch_bounds__(256) void k_gemmx_all(
    const __half* __restrict__ Aall, const _Float16* __restrict__ Bf,
    const float* __restrict__ biasc, __half* __restrict__ Call){
  __shared__ _Float16 aT[32*72];
  int tid = threadIdx.x;
  int r0 = blockIdx.x*32;     // 3750 blocks x 32 rows = 120000 exact
  {
    int r = tid >> 3, c8 = tid & 7;
    *(h8*)&aT[r*72 + c8*8] =
        *(const h8*)&((const _Float16*)(const void*)Aall)[((size_t)(r0+r))*64 + c8*8];
  }
  __syncthreads();
  int wave = tid >> 6, lane = tid & 63;
  int m = wave & 1, nh = wave >> 1;
  int arow = m*16 + (lane & 15);
  int kb = (lane >> 4) * 8;
  h8 a0 = *(const h8*)&aT[arow*72 + kb];
  h8 a1 = *(const h8*)&aT[arow*72 + 32 + kb];
  const h8* B = (const h8*)Bf;
  f32x4 z = {0.f, 0.f, 0.f, 0.f};
  f32x4 acc[8];
  #pragma unroll
  for (int nt = 0; nt < 8; nt++) acc[nt] = z;
  #pragma unroll
  for (int nt = 0; nt < 8; nt++){
    int ntg = nh*8 + nt;
    acc[nt] = __builtin_amdgcn_mfma_f32_16x16x32_f16(a0, B[ntg*64 + lane],        acc[nt], 0,0,0);
    acc[nt] = __builtin_amdgcn_mfma_f32_16x16x32_f16(a1, B[(16 + ntg)*64 + lane], acc[nt], 0,0,0);
  }
  int ccol = lane & 15, crow = (lane >> 4) * 4;
  _Float16* C = (_Float16*)(void*)Call;
  #pragma unroll
  for (int nt = 0; nt < 8; nt++){
    int ntg = nh*8 + nt;
    int col = ntg*16 + ccol;
    float b = biasc[col];
    #pragma unroll
    for (int r = 0; r < 4; r++){
      C[(size_t)(r0 + m*16 + crow + r)*256 + col] = (_Float16)(acc[nt][r] + b);
    }
  }
}

// ---------------- Fused recurrent LSTM (MFMA h-part) + MLP; single-wave blocks ------------
// 1250 blocks x 64 threads, 16 rows each (exact). Wave-synchronous: no barriers.
// Per step: stage gates_x tile -> LDS; gates_h = h @ Whh^T via 32 MFMA (B-frags L2-hot);
// gate-major cols put all 4 gates of (row,unit) in acc[gate*4+us] of ONE lane.
__global__ __launch_bounds__(64) void k_lstm_rec(
    const __half* __restrict__ gatesx,    // [T*N][256] fp16 (bias included)
    const _Float16* __restrict__ Whhf,
    const float* __restrict__ Wfc1, const float* __restrict__ bfc1,
    const float* __restrict__ Wout, const float* __restrict__ bout,
    float* __restrict__ out, int N){
  __shared__ _Float16 gxT[16*264];   // [row][256 + 8 pad]
  __shared__ _Float16 hT[16*68];     // [row][64 + 4 pad]  (A-frag reads conflict-free)
  int lane = threadIdx.x;
  int r0 = blockIdx.x*16;
  for (int i = lane; i < 16*68; i += 64) hT[i] = (_Float16)0.f;
  int ccol = lane & 15, crow = (lane >> 4) * 4;
  int arow_off = (lane & 15)*68 + ((lane >> 4) << 3);
  const h8* Bfrag = (const h8*)Whhf;
  const _Float16* gxb = (const _Float16*)(const void*)gatesx;
  float c[16];
  #pragma unroll
  for (int i = 0; i < 16; i++) c[i] = 0.f;

  for (int t = 0; t < T_STEPS; t++){
    const _Float16* gx = gxb + ((size_t)t*N_NODES + r0)*256;
    #pragma unroll
    for (int it = 0; it < 8; it++){              // 16x256 fp16 tile, coalesced
      int idx = it*64 + lane;
      int r = idx >> 5, c8 = idx & 31;
      *(h8*)&gxT[r*264 + c8*8] = *(const h8*)&gx[(size_t)r*256 + c8*8];
    }
    h8 a0 = *(const h8*)&hT[arow_off];           // h A-frags (prev step; wave-ordered)
    h8 a1 = *(const h8*)&hT[arow_off + 32];
    f32x4 z = {0.f, 0.f, 0.f, 0.f};
    f32x4 acc[16];
    #pragma unroll
    for (int nt = 0; nt < 16; nt++) acc[nt] = z;
    #pragma unroll
    for (int nt = 0; nt < 16; nt++){
      acc[nt] = __builtin_amdgcn_mfma_f32_16x16x32_f16(a0, Bfrag[nt*64 + lane],        acc[nt], 0,0,0);
      acc[nt] = __builtin_amdgcn_mfma_f32_16x16x32_f16(a1, Bfrag[(16 + nt)*64 + lane], acc[nt], 0,0,0);
    }
    #pragma unroll
    for (int us = 0; us < 4; us++){
      int ucol = us*16 + ccol;
      #pragma unroll
      for (int r = 0; r < 4; r++){
        int row = crow + r;
        float gi = acc[us     ][r] + (float)gxT[row*264 +       ucol];
        float gf = acc[4  + us][r] + (float)gxT[row*264 +  64 + ucol];
        float gg = acc[8  + us][r] + (float)gxT[row*264 + 128 + ucol];
        float go = acc[12 + us][r] + (float)gxT[row*264 + 192 + ucol];
        float I = 1.f/(1.f + __expf(-gi));
        float F = 1.f/(1.f + __expf(-gf));
        float O = 1.f/(1.f + __expf(-go));
        float G = fast_tanh(gg);
        float cc = fmaf(F, c[us*4 + r], I*G);
        c[us*4 + r] = cc;
        hT[row*68 + ucol] = (_Float16)(O * fast_tanh(cc));
      }
    }
  }
  // ---- fused MLP head: 4 lanes/row, 8 hidden cols each ----
  int rowm = lane >> 2;            // 0..15
  int cb = (lane & 3) * 8;         // 0,8,16,24
  float a8[8];
  #pragma unroll
  for (int j = 0; j < 8; j++) a8[j] = bfc1[cb + j];
  for (int k = 0; k < 64; k++){
    float hv = (float)hT[rowm*68 + k];
    #pragma unroll
    for (int j = 0; j < 8; j++) a8[j] = fmaf(hv, Wfc1[k*32 + cb + j], a8[j]);
  }
  float v = 0.f;
  #pragma unroll
  for (int j = 0; j < 8; j++) v += fmaxf(a8[j], 0.f) * Wout[cb + j];
  v += __shfl_xor(v, 1, 64);
  v += __shfl_xor(v, 2, 64);
  if ((lane & 3) == 0) out[r0 + rowm] = v + bout[0];
}

// ---------------- launch ----------------
extern "C" void kernel_launch(void* const* d_in, const int* in_sizes, int n_in,
                              void* d_out, int out_size, void* d_ws, size_t ws_size,
                              hipStream_t stream){
  const float* x    = (const float*)d_in[0];
  const int*   edge = (const int*)  d_in[1];
  const float* Wl1  = (const float*)d_in[2];
  const float* Wr1  = (const float*)d_in[3];
  const float* att1 = (const float*)d_in[4];
  const float* b1   = (const float*)d_in[5];
  const float* Wl2  = (const float*)d_in[6];
  const float* Wr2  = (const float*)d_in[7];
  const float* att2 = (const float*)d_in[8];
  const float* b2   = (const float*)d_in[9];
  const float* Wih  = (const float*)d_in[10];
  const float* Whh  = (const float*)d_in[11];
  const float* bih  = (const float*)d_in[12];
  const float* bhh  = (const float*)d_in[13];
  const float* Wfc1 = (const float*)d_in[14];
  const float* bfc1 = (const float*)d_in[15];
  const float* Wout = (const float*)d_in[16];
  const float* bout = (const float*)d_in[17];
  float* out = (float*)d_out;

  const int N = N_NODES;
  const int E = in_sizes[1] / 2;

  char* p = (char*)d_ws;
  auto alloc = [&](size_t bytes)->char*{ char* q = p; p += (bytes + 255) & ~(size_t)255; return q; };
  int* csr       = (int*)alloc((size_t)E*sizeof(int));
  int* row_start = (int*)alloc((size_t)(N+1)*sizeof(int));
  int* deg       = (int*)alloc((size_t)N*sizeof(int));
  int* cursor    = (int*)alloc((size_t)N*sizeof(int));
  const size_t NB = (size_t)T_STEPS*N_NODES*HC;      // 30.72M elems
  char* bufA = alloc(NB*2);   // 61.44MB
  char* bufB = alloc(NB*2);   // 61.44MB
  char* bufC = alloc(NB*2);   // 61.44MB
  float* biasc  = (float*)alloc(256*4);
  _Float16* Bl1f = (_Float16*)alloc(64*256*2);   // MFMA B-frag packs
  _Float16* Br1f = (_Float16*)alloc(64*256*2);
  _Float16* Bl2f = (_Float16*)alloc(256*64*2);
  _Float16* Br2f = (_Float16*)alloc(256*64*2);
  _Float16* Wihf = (_Float16*)alloc(64*256*2);
  _Float16* Whhf = (_Float16*)alloc(64*256*2);

  // Phase aliasing (stream-ordered; each buffer's old tenant dead before reuse):
  __half* xl1h_all = (__half*)bufA;                   // A out, B in
  __half* xr1h_all = (__half*)bufB;                   // A out, B in
  __half* h1_all   = (__half*)bufC;                   // B out, C in
  __half* xl2h_all = (__half*)bufA;                   // C out, D in (xl1h dead)
  __half* xr2h_all = (__half*)(bufA + (size_t)T_STEPS*N_NODES*CH*2);
  __half* h2f_all  = (__half*)bufB;                   // D out (fp16), E in
  __half* gatesx   = (__half*)bufC;                   // E out (h1 dead), rec in

  const int* srcIdx = edge;       // edge_index[0]
  const int* dstIdx = edge + E;   // edge_index[1]

  // deg and cursor are adjacent allocations -> one memset covers both (incl. pad)
  hipMemsetAsync(deg, 0, (size_t)((char*)cursor - (char*)deg) + (size_t)N*4, stream);

  k_count  <<<(E+255)/256, 256, 0, stream>>>(dstIdx, E, deg);
  k_scan   <<<1, 1024, 0, stream>>>(deg, row_start, N);
  k_scatter<<<(E+255)/256, 256, 0, stream>>>(srcIdx, dstIdx, E, row_start, cursor, csr);
  k_sort   <<<(N+3)/4, 256, 0, stream>>>(row_start, csr, N);
  k_packall<<<448, 256, 0, stream>>>(bih, bhh, biasc,
                                     Wl1, Bl1f, Wr1, Br1f, Wl2, Bl2f, Wr2, Br2f,
                                     Wih, Wihf, Whh, Whhf);

  dim3 gGemm((N+31)/32, T_STEPS);
  dim3 gGat ((N+3)/4,  T_STEPS);
  k_gemm1_all<<<gGemm, 256, 0, stream>>>(x, Bl1f, Br1f, xl1h_all, xr1h_all, N);
  k_gat1_all <<<gGat,  256, 0, stream>>>(xl1h_all, xr1h_all, row_start, csr, att1, b1, h1_all, N);
  k_gemm2_all<<<gGemm, 256, 0, stream>>>(h1_all, Bl2f, Br2f, xl2h_all, xr2h_all, N);
  k_gat2_all <<<gGat,  256, 0, stream>>>(xl2h_all, xr2h_all, row_start, csr, att2, b2, h2f_all, N);

  k_gemmx_all<<<(T_STEPS*N)/32, 256, 0, stream>>>(h2f_all, Wihf, biasc, gatesx);
  k_lstm_rec <<<N/16, 64, 0, stream>>>(gatesx, Whhf, Wfc1, bfc1, Wout, bout, out, N);
}